// Round 1
// baseline (5153.560 us; speedup 1.0000x reference)
//
#include <hip/hip_runtime.h>

// ---------------- problem constants ----------------
// S=512 seq, B=64 batch, I=256 in, H=1024 hidden, 4H=4096 gates
// Wx = [W1 W3 W5 W7] (input side), Wh = [W2 W4 W6 W8] (hidden side)
// out: h_seq (512,64,1024) fp32, then h_final (64,1024), c_final (64,1024)

// ---------------- workspace layout (bytes) ----------------
#define OFF_XB    0ul          // bf16 x      [512][64][256]   = 16 MiB
#define OFF_WXP   16777216ul   // bf16 Wx^T   [4096][256]      =  2 MiB (packed [col][k])
#define OFF_WHP   18874368ul   // bf16 Wh^T   [4096][1024]     =  8 MiB (packed [col][k])
#define OFF_BIAS  27262976ul   // f32 bx+bh   [4096]
#define OFF_HBUF  27279360ul   // u32 tagged h {bf16<<16|tag} [2][64][1024] = 512 KiB
// end of workspace usage: 27803648

typedef __attribute__((ext_vector_type(8))) __bf16 bf16x8;
typedef __attribute__((ext_vector_type(4))) float  floatx4;

struct KPtrs { const float* p[17]; };

__device__ __forceinline__ unsigned short f2bf(float f) {  // fp32 -> bf16 RTN-even
  unsigned int u = __float_as_uint(f);
  u += 0x7fffu + ((u >> 16) & 1u);
  return (unsigned short)(u >> 16);
}

__device__ __forceinline__ bf16x8 ld16(const unsigned short* p) {
  return *(const bf16x8*)p;   // cached global_load_dwordx4
}

__device__ __forceinline__ float fsig(float x) {
  return __builtin_amdgcn_rcpf(1.f + __expf(-x));
}
__device__ __forceinline__ float ftanh(float x) {
  return 1.f - 2.f * __builtin_amdgcn_rcpf(1.f + __expf(2.f * x));
}

// L3-coherent (UC, L2-bypassing) relaxed 8B atomic load
__device__ __forceinline__ unsigned long long lduc64(const unsigned int* p) {
  return __hip_atomic_load((const unsigned long long*)p,
                           __ATOMIC_RELAXED, __HIP_MEMORY_SCOPE_AGENT);
}

// One MFMA A-fragment pair worth of tagged words: rows r and r+16, 8 u32 each.
struct Chunk8 { unsigned long long v[8]; };

__device__ __forceinline__ Chunk8 ldchunk(const unsigned int* b0, const unsigned int* b1) {
  Chunk8 c;
#pragma unroll
  for (int i = 0; i < 4; ++i) c.v[i]     = lduc64(b0 + 2 * i);
#pragma unroll
  for (int i = 0; i < 4; ++i) c.v[4 + i] = lduc64(b1 + 2 * i);
  return c;
}

// every 16-bit tag in the chunk must equal tt's tag (tt = tag | tag<<32)
__device__ __forceinline__ bool tags_ok(const Chunk8& c, unsigned long long tt) {
  const unsigned long long M = 0x0000FFFF0000FFFFull;
  unsigned long long d = 0;
#pragma unroll
  for (int i = 0; i < 8; ++i) d |= (c.v[i] ^ tt) & M;
  return d == 0;
}

// strip tags: 4 u64 of tagged words -> 8 packed bf16 (v_perm per pair)
__device__ __forceinline__ bf16x8 unpack4(const unsigned long long* v) {
  unsigned int w[4];
#pragma unroll
  for (int i = 0; i < 4; ++i) {
    unsigned int lo = (unsigned int)v[i];
    unsigned int hi = (unsigned int)(v[i] >> 32);
    // dst = (hi.hi16 << 16) | lo.hi16  -> two consecutive bf16 h values
    w[i] = __builtin_amdgcn_perm(hi, lo, 0x07060302);
  }
  bf16x8 r;
  __builtin_memcpy(&r, w, 16);
  return r;
}

// ---------------- pack/convert + state init ----------------
__global__ void pack_kernel(KPtrs P, unsigned char* ws) {
  unsigned short* xb   = (unsigned short*)(ws + OFF_XB);
  unsigned short* wxp  = (unsigned short*)(ws + OFF_WXP);
  unsigned short* whp  = (unsigned short*)(ws + OFF_WHP);
  float*          bias = (float*)(ws + OFF_BIAS);
  unsigned int*   hb32 = (unsigned int*)(ws + OFF_HBUF);
  const float* x = P.p[0];

  const long tid = (long)blockIdx.x * blockDim.x + threadIdx.x;
  const long nth = (long)gridDim.x * blockDim.x;

  for (long e = tid; e < 8388608l; e += nth)       // x -> bf16, same flat layout
    xb[e] = f2bf(x[e]);
  for (long e = tid; e < 1048576l; e += nth) {     // Wx packed [col][k]
    int c = (int)(e >> 8), i = (int)(e & 255);
    int gg = c >> 10, j = c & 1023;
    wxp[e] = f2bf(P.p[1 + 4 * gg][i * 1024 + j]);  // W1,W3,W5,W7
  }
  for (long e = tid; e < 4194304l; e += nth) {     // Wh packed [col][k]
    int c = (int)(e >> 10), k = (int)(e & 1023);
    int gg = c >> 10, j = c & 1023;
    whp[e] = f2bf(P.p[3 + 4 * gg][k * 1024 + j]);  // W2,W4,W6,W8
  }
  for (long e = tid; e < 4096l; e += nth) {        // bx + bh
    int gg = (int)(e >> 10), j = (int)(e & 1023);
    bias[e] = P.p[2 + 4 * gg][j] + P.p[4 + 4 * gg][j];
  }
  // tagged h double buffer = 0  (h=0, tag=0 == "h_{-1} ready"; UC stores -> L3)
  for (long e = tid; e < 131072l; e += nth)
    __hip_atomic_store(&hb32[e], 0u, __ATOMIC_RELAXED, __HIP_MEMORY_SCOPE_AGENT);
}

// ---------------- persistent fused LSTM ----------------
// 128 blocks = 2 batch-groups (32 batches) x 64 hidden-slices (16 units).
// Self-validating h exchange: each h element is a UC u32 {bf16<<16 | (t+1)}.
// Consumers poll the exact operand words until tag==t; the checked value IS
// the data, so there are NO flags, NO fences, NO ordering stores, and only
// ONE __syncthreads per step (LDS reduce; it also separates this block's
// h-loads from its h-stores, which is what makes double-buffer reuse safe).
// The two batch groups are fully decoupled (each block polls only its own
// group's words).
__global__ void __launch_bounds__(256, 1)
lstm_kernel(const unsigned char* __restrict__ ws, float* __restrict__ out) {
  const unsigned short* xb   = (const unsigned short*)(ws + OFF_XB);
  const unsigned short* wxp  = (const unsigned short*)(ws + OFF_WXP);
  const unsigned short* whp  = (const unsigned short*)(ws + OFF_WHP);
  const float*          bias = (const float*)(ws + OFF_BIAS);
  unsigned int*         hbuf = (unsigned int*)(ws + OFF_HBUF);

  const int tid = threadIdx.x;
  const int wv = tid >> 6, lane = tid & 63;
  const int r = lane & 15, q = lane >> 4;          // MFMA frag row + k-quad
  const int s = blockIdx.x & 63, g = blockIdx.x >> 6;

  __shared__ float pc[2][4][8][64][4];             // double-buffered, 64 KiB

  // ---- preload weights into registers (loop-invariant; lives in AGPR/VGPR) ----
  bf16x8 whf[4][8];   // [nt][kk]
  bf16x8 wxf[4][2];   // [nt][kk]
#pragma unroll
  for (int nt = 0; nt < 4; ++nt) {
    const int c = nt * 1024 + s * 16 + r;
    const unsigned short* whb = whp + (long)c * 1024 + q * 8;
    const unsigned short* wxb = wxp + (long)c * 256 + q * 8;
#pragma unroll
    for (int kk = 0; kk < 8; ++kk) whf[nt][kk] = ld16(whb + wv * 256 + kk * 32);
#pragma unroll
    for (int kk = 0; kk < 2; ++kk) wxf[nt][kk] = ld16(wxb + wv * 64 + kk * 32);
  }

  const unsigned short* xa0 = xb + ((long)g * 32 + r) * 256 + q * 8;

  // epilogue mapping: thread -> (batches ebp, ebp+16 ; hidden j = ej)
  const int ej = tid & 15, ebp = tid >> 4;
  const int lidx = ej | ((ebp >> 2) << 4), rg = ebp & 3;   // C-frag coords
  float bs[4];
#pragma unroll
  for (int gt = 0; gt < 4; ++gt) bs[gt] = bias[gt * 1024 + s * 16 + ej];

  float cst[2] = {0.f, 0.f};

  for (int t = 0; t < 512; ++t) {
    const int pb = t & 1;
    floatx4 acc[2][4];
#pragma unroll
    for (int mt = 0; mt < 2; ++mt)
#pragma unroll
      for (int nt = 0; nt < 4; ++nt) acc[mt][nt] = (floatx4){0.f, 0.f, 0.f, 0.f};

    // tagged h_{t-1} base for this thread (rows r and r+16 of batch group g)
    const unsigned int* ha =
        hbuf + (long)((t - 1) & 1) * 65536 + ((long)g * 32 + r) * 1024 + q * 8;
    const int kbase = wv * 256;

    // issue first h-chunk loads early: latency hides under the x-side MFMAs
    Chunk8 cur = ldchunk(ha + kbase, ha + 16 * 1024 + kbase);

    // ---- x-side K (no dependency; overlaps producers finishing t-1) ----
    const unsigned short* xaT = xa0 + (long)t * (64 * 256);
#pragma unroll
    for (int kk = 0; kk < 2; ++kk) {
      const int k0 = wv * 64 + kk * 32;
      bf16x8 a0 = ld16(xaT + k0);
      bf16x8 a1 = ld16(xaT + 16 * 256 + k0);
#pragma unroll
      for (int nt = 0; nt < 4; ++nt) {
        acc[0][nt] = __builtin_amdgcn_mfma_f32_16x16x32_bf16(a0, wxf[nt][kk], acc[0][nt], 0, 0, 0);
        acc[1][nt] = __builtin_amdgcn_mfma_f32_16x16x32_bf16(a1, wxf[nt][kk], acc[1][nt], 0, 0, 0);
      }
    }

    // ---- h-side K: poll tagged words (tag==t), 1-chunk-ahead pipeline ----
    const unsigned long long tg = (unsigned int)t;
    const unsigned long long tt = tg | (tg << 32);
#pragma unroll
    for (int kk = 0; kk < 8; ++kk) {
      const int k0 = kbase + kk * 32;
      Chunk8 nxt;
      if (kk < 7) nxt = ldchunk(ha + k0 + 32, ha + 16 * 1024 + k0 + 32);
      while (!tags_ok(cur, tt))
        cur = ldchunk(ha + k0, ha + 16 * 1024 + k0);
      bf16x8 a0 = unpack4(&cur.v[0]);
      bf16x8 a1 = unpack4(&cur.v[4]);
#pragma unroll
      for (int nt = 0; nt < 4; ++nt) {
        acc[0][nt] = __builtin_amdgcn_mfma_f32_16x16x32_bf16(a0, whf[nt][kk], acc[0][nt], 0, 0, 0);
        acc[1][nt] = __builtin_amdgcn_mfma_f32_16x16x32_bf16(a1, whf[nt][kk], acc[1][nt], 0, 0, 0);
      }
      if (kk < 7) cur = nxt;
    }

    // ---- cross-wave K reduction via LDS (double-buffered; the ONLY barrier) ----
#pragma unroll
    for (int mt = 0; mt < 2; ++mt)
#pragma unroll
      for (int nt = 0; nt < 4; ++nt)
        *(floatx4*)(&pc[pb][wv][mt * 4 + nt][lane][0]) = acc[mt][nt];
    __syncthreads();

    // ---- gates + state update ----
    float hv[2], cv[2];
#pragma unroll
    for (int e = 0; e < 2; ++e) {
      float gs[4];
#pragma unroll
      for (int gt = 0; gt < 4; ++gt) {
        float sv = bs[gt];
#pragma unroll
        for (int w2 = 0; w2 < 4; ++w2) sv += pc[pb][w2][e * 4 + gt][lidx][rg];
        gs[gt] = sv;
      }
      const float f = fsig(gs[0]), ii = fsig(gs[1]), o = fsig(gs[2]);
      const float cd = ftanh(gs[3]);
      cst[e] = f * cst[e] + ii * cd;
      cv[e] = cst[e];
      hv[e] = o * ftanh(cst[e]);
    }

    // ---- publish tagged h_t (UC write-through to L3; self-validating) ----
    const unsigned int tagw = (unsigned int)(t + 1);
    const int emit = ((ej & 1) == 0);
#pragma unroll
    for (int e = 0; e < 2; ++e) {
      unsigned short hb16 = f2bf(hv[e]);
      unsigned short nb = (unsigned short)__shfl_xor((int)hb16, 1, 64);
      if (emit) {
        unsigned long long pv =
            (unsigned long long)((((unsigned int)hb16) << 16) | tagw) |
            ((unsigned long long)((((unsigned int)nb) << 16) | tagw) << 32);
        unsigned long long* hp = (unsigned long long*)(hbuf + (long)pb * 65536 +
            (long)(g * 32 + e * 16 + ebp) * 1024 + s * 16 + ej);
        __hip_atomic_store(hp, pv, __ATOMIC_RELAXED, __HIP_MEMORY_SCOPE_AGENT);
      }
    }

    // ---- h_seq / finals: normal cached stores (write-back; flushed at end) ----
#pragma unroll
    for (int e = 0; e < 2; ++e) {
      const int bl = e * 16 + ebp;
      const long oidx = (long)t * 65536 + (g * 32 + bl) * 1024 + s * 16 + ej;
      out[oidx] = hv[e];
      if (t == 511) {
        out[33554432l + (g * 32 + bl) * 1024 + s * 16 + ej] = hv[e];
        out[33619968l + (g * 32 + bl) * 1024 + s * 16 + ej] = cv[e];
      }
    }
  }
}

extern "C" void kernel_launch(void* const* d_in, const int* in_sizes, int n_in,
                              void* d_out, int out_size, void* d_ws, size_t ws_size,
                              hipStream_t stream) {
  (void)in_sizes; (void)n_in; (void)out_size; (void)ws_size;
  KPtrs P;
  for (int i = 0; i < 17; ++i) P.p[i] = (const float*)d_in[i];
  pack_kernel<<<dim3(2048), dim3(256), 0, stream>>>(P, (unsigned char*)d_ws);
  lstm_kernel<<<dim3(128), dim3(256), 0, stream>>>((const unsigned char*)d_ws, (float*)d_out);
}